// Round 7
// baseline (678.487 us; speedup 1.0000x reference)
//
#include <hip/hip_runtime.h>
#include <cmath>

// Problem constants
#define BB 2
#define TT 2048
#define CC 1024
#define HH 16
#define DD 64

typedef unsigned short u16;
typedef __attribute__((ext_vector_type(8))) short bf16x8;     // 8 bf16 = 4 VGPRs
typedef __attribute__((ext_vector_type(8))) _Float16 f16x8;   // 8 fp16 = 4 VGPRs
typedef __attribute__((ext_vector_type(4))) float f32x4;

__device__ __forceinline__ u16 f2bf(float f) {
    union { float f; unsigned u; } v; v.f = f;
    return (u16)((v.u + 0x7fff + ((v.u >> 16) & 1)) >> 16);   // RNE
}

__device__ __forceinline__ u16 f2h(float f) {
    union { _Float16 h; u16 u; } v; v.h = (_Float16)f;
    return v.u;
}

// native exp2 (v_exp_f32)
__device__ __forceinline__ float fexp2(float x) {
    float r; asm("v_exp_f32 %0, %1" : "=v"(r) : "v"(x)); return r;
}

__device__ __forceinline__ float gelu_exact(float v) {
    return 0.5f * v * (1.0f + erff(v * 0.70710678118654752440f));
}

__device__ __forceinline__ void glds16(const void* g, void* l) {
    __builtin_amdgcn_global_load_lds(
        (const __attribute__((address_space(1))) void*)g,
        (__attribute__((address_space(3))) void*)l, 16, 0, 0);
}

// ---------------------------------------------------------------------------
// Weight convert + transpose: W [K,N] fp32 -> WT [N,K] bf16. 64x64 tiles.
// ---------------------------------------------------------------------------
__global__ __launch_bounds__(256) void wcvt_kernel(const float* __restrict__ W,
                                                   u16* __restrict__ WT,
                                                   int K, int N) {
    __shared__ u16 t[64][65];
    const int n0 = blockIdx.x * 64, k0 = blockIdx.y * 64;
    const int tid = threadIdx.x;
    const int c = tid & 63;
#pragma unroll
    for (int it = 0; it < 16; ++it) {
        int r = it * 4 + (tid >> 6);
        t[c][r] = f2bf(W[(size_t)(k0 + r) * N + n0 + c]);
    }
    __syncthreads();
#pragma unroll
    for (int it = 0; it < 16; ++it) {
        int r = it * 4 + (tid >> 6);
        WT[(size_t)(n0 + r) * K + k0 + c] = t[r][c];
    }
}

// ---------------------------------------------------------------------------
// LayerNorm: fp32 in, bf16 out. One WAVE per row (no LDS, no barriers).
// ---------------------------------------------------------------------------
__global__ __launch_bounds__(256) void ln_kernel(const float* __restrict__ x,
                                                 const float* __restrict__ w,
                                                 const float* __restrict__ b,
                                                 u16* __restrict__ out) {
    const int tid = threadIdx.x;
    const int lane = tid & 63;
    const int row = blockIdx.x * 4 + (tid >> 6);
    const float* xr = x + (size_t)row * CC;
    u16* orow = out + (size_t)row * CC;

    float4 v[4];
#pragma unroll
    for (int k = 0; k < 4; ++k)
        v[k] = *reinterpret_cast<const float4*>(xr + k * 256 + lane * 4);

    float s = 0.f;
#pragma unroll
    for (int k = 0; k < 4; ++k) s += v[k].x + v[k].y + v[k].z + v[k].w;
#pragma unroll
    for (int off = 1; off < 64; off <<= 1) s += __shfl_xor(s, off);
    const float mean = s * (1.0f / CC);

    float sq = 0.f;
#pragma unroll
    for (int k = 0; k < 4; ++k) {
        float dx = v[k].x - mean, dy = v[k].y - mean, dz = v[k].z - mean, dw = v[k].w - mean;
        sq += dx * dx + dy * dy + dz * dz + dw * dw;
    }
#pragma unroll
    for (int off = 1; off < 64; off <<= 1) sq += __shfl_xor(sq, off);
    const float rstd = rsqrtf(sq * (1.0f / CC) + 1e-5f);

#pragma unroll
    for (int k = 0; k < 4; ++k) {
        const int c = k * 256 + lane * 4;
        float4 w4 = *reinterpret_cast<const float4*>(w + c);
        float4 b4 = *reinterpret_cast<const float4*>(b + c);
        ushort4 o = make_ushort4(f2bf((v[k].x - mean) * rstd * w4.x + b4.x),
                                 f2bf((v[k].y - mean) * rstd * w4.y + b4.y),
                                 f2bf((v[k].z - mean) * rstd * w4.z + b4.z),
                                 f2bf((v[k].w - mean) * rstd * w4.w + b4.w));
        *reinterpret_cast<ushort4*>(orow + c) = o;
    }
}

// ---------------------------------------------------------------------------
// bf16 MFMA GEMM, 512 threads / 8 waves, BK=64, double-buffered LDS with
// issue-early staging (T3-min): stage(t+1) BEFORE compute(t); one barrier
// per K-tile (compiler's vmcnt(0) drain lands after a full compute phase).
// XOR-swizzled staging (pre-swizzled global source, linear LDS dest).
// EPI: 0=bias fp32, 1=bias+GELU bf16, 2=bias+residual fp32, 3=qkv-split:
//   Q cols -> fp32 [M][1024]; K cols -> kh fp16 [M][1024] row-major;
//   V cols -> vh fp16 [M][1024] row-major (coalesced; no scatter).
// ---------------------------------------------------------------------------
template <int EPI, int OUTBF, int WM, int WN, int FI, int FJ>
__global__ __launch_bounds__(512) void gemm_mfma(const u16* __restrict__ A,
                                                 const u16* __restrict__ BT,
                                                 const float* __restrict__ bias,
                                                 const float* __restrict__ res,
                                                 void* __restrict__ out,
                                                 u16* __restrict__ kh,
                                                 u16* __restrict__ vh,
                                                 int M, int N, int K) {
    constexpr int TM = WM * FI * 16;       // 256 or 128
    constexpr int TN = WN * FJ * 16;       // 128
    __shared__ u16 As[2][TM * 64];
    __shared__ u16 Bs[2][TN * 64];

    const int tid = threadIdx.x;
    const int lane = tid & 63;
    const int w = tid >> 6;                 // wave 0..7
    const int wr = w / WN, wc = w % WN;
    const int m16 = lane & 15;
    const int quad = lane >> 4;

    const int bm = blockIdx.y * TM;
    const int bn = blockIdx.x * TN;

    auto stage = [&](int buf, int kt) {
        const int k0 = kt * 64;
#pragma unroll
        for (int it = 0; it < TM / 64; ++it) {
            int c = w * (TM / 64) + it;        // 1KB chunk id (8 rows)
            int q = c * 64 + lane;
            int row = q >> 3;
            int col = ((q & 7) ^ (row & 7)) * 8;
            glds16(&A[(size_t)(bm + row) * K + k0 + col], &As[buf][c * 512]);
        }
#pragma unroll
        for (int it = 0; it < TN / 64; ++it) {
            int c = w * (TN / 64) + it;
            int q = c * 64 + lane;
            int row = q >> 3;
            int col = ((q & 7) ^ (row & 7)) * 8;
            glds16(&BT[(size_t)(bn + row) * K + k0 + col], &Bs[buf][c * 512]);
        }
    };

    f32x4 acc[FI][FJ] = {};
    const int NT = K >> 6;
    stage(0, 0);
    __syncthreads();                        // buf0 ready
    int cur = 0;
    for (int kt = 0; kt < NT; ++kt) {
        if (kt + 1 < NT) stage(cur ^ 1, kt + 1);   // overlap with compute below
#pragma unroll
        for (int ks = 0; ks < 2; ++ks) {
            const int co = (ks * 32 + quad * 8) ^ ((m16 & 7) << 3);
            bf16x8 a[FI], b[FJ];
#pragma unroll
            for (int i = 0; i < FI; ++i)
                a[i] = *(const bf16x8*)&As[cur][(wr * FI * 16 + 16 * i + m16) * 64 + co];
#pragma unroll
            for (int j = 0; j < FJ; ++j)
                b[j] = *(const bf16x8*)&Bs[cur][(wc * FJ * 16 + 16 * j + m16) * 64 + co];
#pragma unroll
            for (int i = 0; i < FI; ++i)
#pragma unroll
                for (int j = 0; j < FJ; ++j)
                    acc[i][j] = __builtin_amdgcn_mfma_f32_16x16x32_bf16(a[i], b[j], acc[i][j], 0, 0, 0);
        }
        __syncthreads();                    // drains vmcnt -> buf[cur^1] staged
        cur ^= 1;
    }

#pragma unroll
    for (int i = 0; i < FI; ++i) {
        const int row = bm + wr * FI * 16 + 16 * i + quad * 4;
#pragma unroll
        for (int j = 0; j < FJ; ++j) {
            const int col = bn + wc * FJ * 16 + 16 * j + m16;
            const float bv = bias[col];
#pragma unroll
            for (int r = 0; r < 4; ++r) {
                float v = acc[i][j][r] + bv;
                if (EPI == 1) v = gelu_exact(v);
                if (EPI == 2) v += res[(size_t)(row + r) * N + col];
                if (EPI == 3) {
                    if (col < CC) ((float*)out)[(size_t)(row + r) * CC + col] = v;
                    else if (col < 2 * CC) kh[(size_t)(row + r) * CC + (col - CC)] = f2h(v);
                    else vh[(size_t)(row + r) * CC + (col - 2 * CC)] = f2h(v);
                } else if (OUTBF) {
                    ((u16*)out)[(size_t)(row + r) * N + col] = f2bf(v);
                } else {
                    ((float*)out)[(size_t)(row + r) * N + col] = v;
                }
            }
        }
    }
}

// ---------------------------------------------------------------------------
// V transpose: Vh fp16 [B*T][C] -> VTt fp16 [(b*H+h)*D + d][T]. 64x64 tiles.
// ---------------------------------------------------------------------------
__global__ __launch_bounds__(256) void vtr_kernel(const u16* __restrict__ Vh,
                                                  u16* __restrict__ VTt) {
    const int t0 = blockIdx.x * 64;
    const int h = blockIdx.y;
    const int b = blockIdx.z;
    const int tid = threadIdx.x;
    __shared__ u16 tl[64][65];
#pragma unroll
    for (int it = 0; it < 4; ++it) {
        int e = tid + it * 256;
        int r = e >> 4, c4 = (e & 15) * 4;
        ushort4 v = *reinterpret_cast<const ushort4*>(
            &Vh[(size_t)(b * TT + t0 + r) * CC + h * DD + c4]);
        tl[c4 + 0][r] = v.x; tl[c4 + 1][r] = v.y; tl[c4 + 2][r] = v.z; tl[c4 + 3][r] = v.w;
    }
    __syncthreads();
#pragma unroll
    for (int it = 0; it < 4; ++it) {
        int e = tid + it * 256;
        int d = e >> 4, s4 = (e & 15) * 4;
        ushort4 o = make_ushort4(tl[d][s4], tl[d][s4 + 1], tl[d][s4 + 2], tl[d][s4 + 3]);
        *reinterpret_cast<ushort4*>(&VTt[(size_t)((b * HH + h) * DD + d) * TT + t0 + s4]) = o;
    }
}

// ---------------------------------------------------------------------------
// MFMA two-pass causal attention (fp16, dbuf, no-max softmax, native exp2).
// K/VT staged straight from row-major fp16 buffers via per-lane PRE-SWIZZLED
// global addresses (global_load_lds source is per-lane; LDS dest linear).
// LDS layout/read side identical to R6 (XOR swizzle col ^= (row&7)<<3).
// ---------------------------------------------------------------------------
__global__ __launch_bounds__(256) void attn_kernel(const float* __restrict__ Qf,
                                                   const u16* __restrict__ Kh,
                                                   const u16* __restrict__ VTt,
                                                   float* __restrict__ attn_mean,
                                                   u16* __restrict__ attn_out) {
    const int lid = blockIdx.x;
    const int u = lid & 255;
    const int h = u & 15;
    const int ta = u >> 4;
    const int tt = (lid < 256) ? ta : 31 - ta;
    const int t0 = tt * 64;

    const int tid = threadIdx.x;
    const int lane = tid & 63;
    const int w = tid >> 6;                 // wave 0..3
    const int m16 = lane & 15;
    const int quad = lane >> 4;

    __shared__ u16 smem[2][4][4096];        // 64 KB: [buf][K0,K1,V0,V1]
    __shared__ u16 Pm[2][4096];             // 16 KB: P slots (b0, b1)

    const int arow = w * 16 + m16;          // wave-private fragment row
    const int sw = (m16 & 7) << 3;          // read-side swizzle (u16 units)
    const int rbase = w * 16 + quad * 4;    // C/D row base within tile

    auto KSL = [&](int buf, int b) -> const u16 (*)[64] { return (const u16(*)[64]) & smem[buf][b][0]; };
    auto VSL = [&](int buf, int b) -> const u16 (*)[64] { return (const u16(*)[64]) & smem[buf][2 + b][0]; };

    // stage K tile (64 rows x 64 d) for (b, st): 8 chunks of 1KB, wave w: 2.
    auto stage_K = [&](int buf, int b, int st) {
#pragma unroll
        for (int it = 0; it < 2; ++it) {
            int c = w * 2 + it;
            int s = c * 8 + (lane >> 3);
            int scol = ((lane & 7) * 8) ^ ((s & 7) << 3);
            glds16(&Kh[(size_t)(b * TT + st * 64 + s) * CC + h * DD + scol],
                   &smem[buf][b][c * 512]);
        }
    };
    auto stage_V = [&](int buf, int b, int st) {
#pragma unroll
        for (int it = 0; it < 2; ++it) {
            int c = w * 2 + it;
            int d = c * 8 + (lane >> 3);
            int scol = ((lane & 7) * 8) ^ ((d & 7) << 3);
            glds16(&VTt[(size_t)((b * HH + h) * DD + d) * TT + st * 64 + scol],
                   &smem[buf][2 + b][c * 512]);
        }
    };
    auto stage_K2 = [&](int buf, int st) { stage_K(buf, 0, st); stage_K(buf, 1, st); };
    auto stage_KV4 = [&](int buf, int st) {
        stage_K2(buf, st); stage_V(buf, 0, st); stage_V(buf, 1, st);
    };

    // ---- Q fragments in registers, scaled by log2e/sqrt(D) ----
    const float QSCALE = 0.125f * 1.4426950408889634f;
    f16x8 qh[2][2];
#pragma unroll
    for (int b = 0; b < 2; ++b) {
        const float* qp = Qf + (size_t)(b * TT + t0 + arow) * CC + h * DD;
#pragma unroll
        for (int ks = 0; ks < 2; ++ks) {
            float4 v0 = *reinterpret_cast<const float4*>(qp + ks * 32 + quad * 8);
            float4 v1 = *reinterpret_cast<const float4*>(qp + ks * 32 + quad * 8 + 4);
            float f[8] = {v0.x, v0.y, v0.z, v0.w, v1.x, v1.y, v1.z, v1.w};
            union { f16x8 v; u16 s[8]; } H;
#pragma unroll
            for (int i = 0; i < 8; ++i) H.s[i] = f2h(f[i] * QSCALE);
            qh[b][ks] = H.v;
        }
    }

    auto compute_S = [&](const f16x8 (&QH)[2], const u16 (*KT)[64],
                         f32x4 (&acc)[4], bool diag) {
        __builtin_amdgcn_s_setprio(1);
#pragma unroll
        for (int ks = 0; ks < 2; ++ks) {
            const int co = (ks * 32 + quad * 8) ^ sw;
#pragma unroll
            for (int j = 0; j < 4; ++j) {
                f16x8 bh = *(const f16x8*)&KT[j * 16 + m16][co];
                acc[j] = __builtin_amdgcn_mfma_f32_16x16x32_f16(QH[ks], bh, acc[j], 0, 0, 0);
            }
        }
        __builtin_amdgcn_s_setprio(0);
        if (diag) {
#pragma unroll
            for (int j = 0; j < 4; ++j)
#pragma unroll
                for (int r = 0; r < 4; ++r)
                    if (j * 16 + m16 > rbase + r) acc[j][r] = -INFINITY;
        }
    };

    auto pv_acc = [&](f32x4 (&O)[4], const u16* Pp, const u16 (*VT)[64]) {
        __builtin_amdgcn_s_setprio(1);
#pragma unroll
        for (int ks = 0; ks < 2; ++ks) {
            const int co = (ks * 32 + quad * 8) ^ sw;
            f16x8 a = *(const f16x8*)&Pp[arow * 64 + co];
#pragma unroll
            for (int j = 0; j < 4; ++j) {
                f16x8 bv = *(const f16x8*)&VT[j * 16 + m16][co];
                O[j] = __builtin_amdgcn_mfma_f32_16x16x32_f16(a, bv, O[j], 0, 0, 0);
            }
        }
        __builtin_amdgcn_s_setprio(0);
    };

    // ---- Pass A: accumulate l partials per lane; reduce once at the end ----
    float l_r[2][4] = {};
    stage_K2(0, 0);
    for (int st = 0; st <= tt; ++st) {
        const int cur = st & 1;
        __syncthreads();
        if (st + 1 <= tt) stage_K2(cur ^ 1, st + 1);
        const bool diag = (st == tt);
#pragma unroll
        for (int b = 0; b < 2; ++b) {
            f32x4 acc[4] = {};
            compute_S(qh[b], KSL(cur, b), acc, diag);
#pragma unroll
            for (int r = 0; r < 4; ++r)
                l_r[b][r] += (fexp2(acc[0][r]) + fexp2(acc[1][r])) +
                             (fexp2(acc[2][r]) + fexp2(acc[3][r]));
        }
    }
    __syncthreads();
#pragma unroll
    for (int b = 0; b < 2; ++b)
#pragma unroll
        for (int r = 0; r < 4; ++r) {
            float s = l_r[b][r];
            s += __shfl_xor(s, 1);
            s += __shfl_xor(s, 2);
            s += __shfl_xor(s, 4);
            s += __shfl_xor(s, 8);
            l_r[b][r] = 1.0f / s;
        }

    // ---- Pass B: recompute S, write attn_mean, PV via MFMA (1 barrier/step) ----
    f32x4 O0[4] = {}, O1[4] = {};
    stage_KV4(0, 0);
    for (int st = 0; st <= tt; ++st) {
        const int cur = st & 1;
        const int s0 = st * 64;
        const bool diag = (st == tt);
        __syncthreads();
        if (st + 1 <= tt) stage_KV4(cur ^ 1, st + 1);

        f32x4 a0[4] = {}, a1[4] = {};
        compute_S(qh[0], KSL(cur, 0), a0, diag);
        compute_S(qh[1], KSL(cur, 1), a1, diag);

#pragma unroll
        for (int j = 0; j < 4; ++j)
#pragma unroll
            for (int r = 0; r < 4; ++r) {
                a0[j][r] = fexp2(a0[j][r]) * l_r[0][r];
                a1[j][r] = fexp2(a1[j][r]) * l_r[1][r];
            }

        // attn_mean = 0.5*(P0+P1)
#pragma unroll
        for (int r = 0; r < 4; ++r) {
            float* mrow = attn_mean + ((size_t)h * TT + t0 + rbase + r) * TT + s0;
#pragma unroll
            for (int j = 0; j < 4; ++j)
                mrow[j * 16 + m16] = 0.5f * (a0[j][r] + a1[j][r]);
        }

        // P (fp16, swizzled) into dedicated slots; rows wave-private
#pragma unroll
        for (int r = 0; r < 4; ++r) {
            const int prow = rbase + r;
            const int psw = (prow & 7) << 3;
#pragma unroll
            for (int j = 0; j < 4; ++j) {
                Pm[0][prow * 64 + ((j * 16 + m16) ^ psw)] = f2h(a0[j][r]);
                Pm[1][prow * 64 + ((j * 16 + m16) ^ psw)] = f2h(a1[j][r]);
            }
        }
        pv_acc(O0, &Pm[0][0], VSL(cur, 0));
        pv_acc(O1, &Pm[1][0], VSL(cur, 1));
    }

    // ---- epilogue: att_o bf16 ----
#pragma unroll
    for (int r = 0; r < 4; ++r) {
        const int trow = t0 + rbase + r;
#pragma unroll
        for (int j = 0; j < 4; ++j) {
            attn_out[((size_t)0 * TT + trow) * CC + h * DD + j * 16 + m16] = f2bf(O0[j][r]);
            attn_out[((size_t)1 * TT + trow) * CC + h * DD + j * 16 + m16] = f2bf(O1[j][r]);
        }
    }

    // zero upper triangle of attn_mean rows owned by this block
    const int c0 = (tt + 1) * 64;
    const float4 z4 = make_float4(0.f, 0.f, 0.f, 0.f);
    for (int r = 0; r < 64; ++r) {
        float* row = attn_mean + ((size_t)h * TT + t0 + r) * TT;
        for (int c = c0 + tid * 4; c < TT; c += 1024)
            *reinterpret_cast<float4*>(row + c) = z4;
    }
}

// ---------------------------------------------------------------------------
extern "C" void kernel_launch(void* const* d_in, const int* in_sizes, int n_in,
                              void* d_out, int out_size, void* d_ws, size_t ws_size,
                              hipStream_t stream) {
    const float* x      = (const float*)d_in[0];
    const float* ln1_w  = (const float*)d_in[1];
    const float* ln1_b  = (const float*)d_in[2];
    const float* w_qkv  = (const float*)d_in[3];
    const float* b_qkv  = (const float*)d_in[4];
    const float* w_proj = (const float*)d_in[5];
    const float* b_proj = (const float*)d_in[6];
    const float* ln2_w  = (const float*)d_in[7];
    const float* ln2_b  = (const float*)d_in[8];
    const float* w_fc   = (const float*)d_in[9];
    const float* b_fc   = (const float*)d_in[10];
    const float* w_fc2  = (const float*)d_in[11];
    const float* b_fc2  = (const float*)d_in[12];

    float* out_x    = (float*)d_out;
    float* out_attn = out_x + (size_t)BB * TT * CC;

    char* wp = (char*)d_ws;
    u16* wT_qkv = (u16*)wp;  wp += (size_t)3072 * 1024 * 2;
    u16* wT_proj = (u16*)wp; wp += (size_t)1024 * 1024 * 2;
    u16* wT_fc  = (u16*)wp;  wp += (size_t)4096 * 1024 * 2;
    u16* wT_fc2 = (u16*)wp;  wp += (size_t)1024 * 4096 * 2;
    u16* h_ln   = (u16*)wp;  wp += (size_t)4096 * 1024 * 2;
    u16* att_o  = (u16*)wp;  wp += (size_t)4096 * 1024 * 2;
    u16* h2     = (u16*)wp;  wp += (size_t)4096 * 4096 * 2;
    float* Qf   = (float*)wp; wp += (size_t)4096 * 1024 * 4;
    float* x1   = (float*)wp; wp += (size_t)4096 * 1024 * 4;

    // attn staging buffers overlay h2 (dead until step 6): 3 x 8 MB = 24 MB
    u16* Kh  = h2;
    u16* Vh  = Kh + (size_t)4096 * 1024;
    u16* VTt = Vh + (size_t)4096 * 1024;

    const int M = BB * TT;   // 4096

    // weight convert+transpose (bf16, [N,K])
    wcvt_kernel<<<dim3(3072 / 64, 1024 / 64), 256, 0, stream>>>(w_qkv, wT_qkv, 1024, 3072);
    wcvt_kernel<<<dim3(1024 / 64, 1024 / 64), 256, 0, stream>>>(w_proj, wT_proj, 1024, 1024);
    wcvt_kernel<<<dim3(4096 / 64, 1024 / 64), 256, 0, stream>>>(w_fc, wT_fc, 1024, 4096);
    wcvt_kernel<<<dim3(1024 / 64, 4096 / 64), 256, 0, stream>>>(w_fc2, wT_fc2, 4096, 1024);

    // 1. LN1 -> bf16
    ln_kernel<<<M / 4, 256, 0, stream>>>(x, ln1_w, ln1_b, h_ln);
    // 2. qkv GEMM (256x128 tiles, 8 waves): Q->fp32 Qf, K->Kh fp16, V->Vh fp16
    gemm_mfma<3, 0, 2, 4, 8, 2><<<dim3(3072 / 128, M / 256), 512, 0, stream>>>(
        h_ln, wT_qkv, b_qkv, nullptr, Qf, Kh, Vh, M, 3072, 1024);
    // 2b. V transpose (fp16 -> fp16 [b,h,d][T])
    vtr_kernel<<<dim3(TT / 64, HH, BB), 256, 0, stream>>>(Vh, VTt);
    // 3. attention
    attn_kernel<<<512, 256, 0, stream>>>(Qf, Kh, VTt, out_attn, att_o);
    // 4. x1 = x + att_o @ w_proj + b_proj  (128x128 tiles, 8 waves)
    gemm_mfma<2, 0, 2, 4, 4, 2><<<dim3(1024 / 128, M / 128), 512, 0, stream>>>(
        att_o, wT_proj, b_proj, x, x1, nullptr, nullptr, M, 1024, 1024);
    // 5. LN2 -> bf16
    ln_kernel<<<M / 4, 256, 0, stream>>>(x1, ln2_w, ln2_b, h_ln);
    // 6. h2 = gelu(h_ln @ w_fc + b_fc)  (256x128 tiles, 8 waves)
    gemm_mfma<1, 1, 2, 4, 8, 2><<<dim3(4096 / 128, M / 256), 512, 0, stream>>>(
        h_ln, wT_fc, b_fc, nullptr, h2, nullptr, nullptr, M, 4096, 1024);
    // 7. out_x = x1 + h2 @ w_fc2 + b_fc2  (128x128 tiles, 8 waves)
    gemm_mfma<2, 0, 2, 4, 4, 2><<<dim3(1024 / 128, M / 128), 512, 0, stream>>>(
        h2, wT_fc2, b_fc2, x1, out_x, nullptr, nullptr, M, 1024, 4096);
}

// Round 8
// 644.823 us; speedup vs baseline: 1.0522x; 1.0522x over previous
//
#include <hip/hip_runtime.h>
#include <cmath>

// Problem constants
#define BB 2
#define TT 2048
#define CC 1024
#define HH 16
#define DD 64

typedef unsigned short u16;
typedef __attribute__((ext_vector_type(8))) short bf16x8;     // 8 bf16 = 4 VGPRs
typedef __attribute__((ext_vector_type(8))) _Float16 f16x8;   // 8 fp16 = 4 VGPRs
typedef __attribute__((ext_vector_type(4))) float f32x4;

__device__ __forceinline__ u16 f2bf(float f) {
    union { float f; unsigned u; } v; v.f = f;
    return (u16)((v.u + 0x7fff + ((v.u >> 16) & 1)) >> 16);   // RNE
}

__device__ __forceinline__ u16 f2h(float f) {
    union { _Float16 h; u16 u; } v; v.h = (_Float16)f;
    return v.u;
}

// native exp2 (v_exp_f32)
__device__ __forceinline__ float fexp2(float x) {
    float r; asm("v_exp_f32 %0, %1" : "=v"(r) : "v"(x)); return r;
}

__device__ __forceinline__ float gelu_exact(float v) {
    return 0.5f * v * (1.0f + erff(v * 0.70710678118654752440f));
}

__device__ __forceinline__ void glds16(const void* g, void* l) {
    __builtin_amdgcn_global_load_lds(
        (const __attribute__((address_space(1))) void*)g,
        (__attribute__((address_space(3))) void*)l, 16, 0, 0);
}

// ---------------------------------------------------------------------------
// Weight convert + transpose: W [K,N] fp32 -> WT [N,K] bf16. 64x64 tiles.
// ---------------------------------------------------------------------------
__global__ __launch_bounds__(256) void wcvt_kernel(const float* __restrict__ W,
                                                   u16* __restrict__ WT,
                                                   int K, int N) {
    __shared__ u16 t[64][65];
    const int n0 = blockIdx.x * 64, k0 = blockIdx.y * 64;
    const int tid = threadIdx.x;
    const int c = tid & 63;
#pragma unroll
    for (int it = 0; it < 16; ++it) {
        int r = it * 4 + (tid >> 6);
        t[c][r] = f2bf(W[(size_t)(k0 + r) * N + n0 + c]);
    }
    __syncthreads();
#pragma unroll
    for (int it = 0; it < 16; ++it) {
        int r = it * 4 + (tid >> 6);
        WT[(size_t)(n0 + r) * K + k0 + c] = t[r][c];
    }
}

// ---------------------------------------------------------------------------
// LayerNorm: fp32 in, bf16 out. One WAVE per row (no LDS, no barriers).
// ---------------------------------------------------------------------------
__global__ __launch_bounds__(256) void ln_kernel(const float* __restrict__ x,
                                                 const float* __restrict__ w,
                                                 const float* __restrict__ b,
                                                 u16* __restrict__ out) {
    const int tid = threadIdx.x;
    const int lane = tid & 63;
    const int row = blockIdx.x * 4 + (tid >> 6);
    const float* xr = x + (size_t)row * CC;
    u16* orow = out + (size_t)row * CC;

    float4 v[4];
#pragma unroll
    for (int k = 0; k < 4; ++k)
        v[k] = *reinterpret_cast<const float4*>(xr + k * 256 + lane * 4);

    float s = 0.f;
#pragma unroll
    for (int k = 0; k < 4; ++k) s += v[k].x + v[k].y + v[k].z + v[k].w;
#pragma unroll
    for (int off = 1; off < 64; off <<= 1) s += __shfl_xor(s, off);
    const float mean = s * (1.0f / CC);

    float sq = 0.f;
#pragma unroll
    for (int k = 0; k < 4; ++k) {
        float dx = v[k].x - mean, dy = v[k].y - mean, dz = v[k].z - mean, dw = v[k].w - mean;
        sq += dx * dx + dy * dy + dz * dz + dw * dw;
    }
#pragma unroll
    for (int off = 1; off < 64; off <<= 1) sq += __shfl_xor(sq, off);
    const float rstd = rsqrtf(sq * (1.0f / CC) + 1e-5f);

#pragma unroll
    for (int k = 0; k < 4; ++k) {
        const int c = k * 256 + lane * 4;
        float4 w4 = *reinterpret_cast<const float4*>(w + c);
        float4 b4 = *reinterpret_cast<const float4*>(b + c);
        ushort4 o = make_ushort4(f2bf((v[k].x - mean) * rstd * w4.x + b4.x),
                                 f2bf((v[k].y - mean) * rstd * w4.y + b4.y),
                                 f2bf((v[k].z - mean) * rstd * w4.z + b4.z),
                                 f2bf((v[k].w - mean) * rstd * w4.w + b4.w));
        *reinterpret_cast<ushort4*>(orow + c) = o;
    }
}

// ---------------------------------------------------------------------------
// 256x256 2-phase dbuf GEMM, 512 threads / 8 waves (2M x 4N), BK=64.
// LDS 128KB -> 1 block/CU; grids sized <= 256 so no tail round.
// stage(t+1) issued BEFORE compute(t); single barrier/iter drains it after
// 64 MFMAs of cover. XOR-swizzled via pre-swizzled global source.
// EPI: 1=bias+GELU bf16 out; 3=qkv-split (Q fp32 / K fp16 / V fp16).
// ---------------------------------------------------------------------------
template <int EPI>
__global__ __launch_bounds__(512, 2) void gemm_db(const u16* __restrict__ A,
                                                  const u16* __restrict__ BT,
                                                  const float* __restrict__ bias,
                                                  void* __restrict__ out,
                                                  u16* __restrict__ kh,
                                                  u16* __restrict__ vh,
                                                  int M, int N, int K) {
    constexpr int TM = 256, TN = 256;
    __shared__ u16 As[2][TM * 64];      // 64 KB
    __shared__ u16 Bs[2][TN * 64];      // 64 KB

    const int tid = threadIdx.x;
    const int lane = tid & 63;
    const int w = tid >> 6;                 // wave 0..7
    const int wr = w >> 2, wc = w & 3;      // 2M x 4N
    const int m16 = lane & 15;
    const int quad = lane >> 4;

    const int bm = blockIdx.y * TM;
    const int bn = blockIdx.x * TN;

    auto stage = [&](int buf, int kt) {
        const int k0 = kt * 64;
#pragma unroll
        for (int it = 0; it < 4; ++it) {       // A: 32 chunks of 1KB, 4/wave
            int c = w * 4 + it;
            int q = c * 64 + lane;
            int row = q >> 3;
            int col = ((q & 7) ^ (row & 7)) * 8;
            glds16(&A[(size_t)(bm + row) * K + k0 + col], &As[buf][c * 512]);
        }
#pragma unroll
        for (int it = 0; it < 4; ++it) {       // B: 32 chunks
            int c = w * 4 + it;
            int q = c * 64 + lane;
            int row = q >> 3;
            int col = ((q & 7) ^ (row & 7)) * 8;
            glds16(&BT[(size_t)(bn + row) * K + k0 + col], &Bs[buf][c * 512]);
        }
    };

    f32x4 acc[8][4] = {};
    const int NT = K >> 6;
    stage(0, 0);
    __syncthreads();
    int cur = 0;
    for (int kt = 0; kt < NT; ++kt) {
        if (kt + 1 < NT) stage(cur ^ 1, kt + 1);
#pragma unroll
        for (int ks = 0; ks < 2; ++ks) {
            const int co = (ks * 32 + quad * 8) ^ ((m16 & 7) << 3);
            bf16x8 a[8], b[4];
#pragma unroll
            for (int i = 0; i < 8; ++i)
                a[i] = *(const bf16x8*)&As[cur][(wr * 128 + 16 * i + m16) * 64 + co];
#pragma unroll
            for (int j = 0; j < 4; ++j)
                b[j] = *(const bf16x8*)&Bs[cur][(wc * 64 + 16 * j + m16) * 64 + co];
            __builtin_amdgcn_s_setprio(1);
#pragma unroll
            for (int i = 0; i < 8; ++i)
#pragma unroll
                for (int j = 0; j < 4; ++j)
                    acc[i][j] = __builtin_amdgcn_mfma_f32_16x16x32_bf16(a[i], b[j], acc[i][j], 0, 0, 0);
            __builtin_amdgcn_s_setprio(0);
        }
        __syncthreads();                     // drains stage(kt+1); buf swap safe
        cur ^= 1;
    }

#pragma unroll
    for (int i = 0; i < 8; ++i) {
        const int row = bm + wr * 128 + 16 * i + quad * 4;
#pragma unroll
        for (int j = 0; j < 4; ++j) {
            const int col = bn + wc * 64 + 16 * j + m16;
            const float bv = bias[col];
#pragma unroll
            for (int r = 0; r < 4; ++r) {
                float v = acc[i][j][r] + bv;
                if (EPI == 1) {
                    v = gelu_exact(v);
                    ((u16*)out)[(size_t)(row + r) * N + col] = f2bf(v);
                } else {  // EPI == 3
                    if (col < CC) ((float*)out)[(size_t)(row + r) * CC + col] = v;
                    else if (col < 2 * CC) kh[(size_t)(row + r) * CC + (col - CC)] = f2h(v);
                    else vh[(size_t)(row + r) * CC + (col - 2 * CC)] = f2h(v);
                }
            }
        }
    }
}

// ---------------------------------------------------------------------------
// 4-wave 128x64 2-barrier GEMM (R6-exact known-good): bias+residual fp32 out.
// ---------------------------------------------------------------------------
__global__ __launch_bounds__(256) void gemm_sm(const u16* __restrict__ A,
                                               const u16* __restrict__ BT,
                                               const float* __restrict__ bias,
                                               const float* __restrict__ res,
                                               float* __restrict__ out,
                                               int M, int N, int K) {
    constexpr int TM = 128, TN = 64;
    __shared__ u16 As[TM * 64];
    __shared__ u16 Bs[TN * 64];

    const int tid = threadIdx.x;
    const int lane = tid & 63;
    const int w = tid >> 6;                 // wave 0..3 (4M x 1N)
    const int m16 = lane & 15;
    const int quad = lane >> 4;

    const int bm = blockIdx.y * TM;
    const int bn = blockIdx.x * TN;

    f32x4 acc[2][4] = {};

    for (int k0 = 0; k0 < K; k0 += 64) {
#pragma unroll
        for (int it = 0; it < 4; ++it) {       // A: 16 chunks
            int c = w * 4 + it;
            int q = c * 64 + lane;
            int row = q >> 3;
            int col = ((q & 7) ^ (row & 7)) * 8;
            glds16(&A[(size_t)(bm + row) * K + k0 + col], &As[c * 512]);
        }
#pragma unroll
        for (int it = 0; it < 2; ++it) {       // B: 8 chunks
            int c = w * 2 + it;
            int q = c * 64 + lane;
            int row = q >> 3;
            int col = ((q & 7) ^ (row & 7)) * 8;
            glds16(&BT[(size_t)(bn + row) * K + k0 + col], &Bs[c * 512]);
        }
        __syncthreads();

#pragma unroll
        for (int ks = 0; ks < 2; ++ks) {
            const int co = (ks * 32 + quad * 8) ^ ((m16 & 7) << 3);
            bf16x8 a[2], b[4];
#pragma unroll
            for (int i = 0; i < 2; ++i)
                a[i] = *(const bf16x8*)&As[(w * 32 + 16 * i + m16) * 64 + co];
#pragma unroll
            for (int j = 0; j < 4; ++j)
                b[j] = *(const bf16x8*)&Bs[(16 * j + m16) * 64 + co];
#pragma unroll
            for (int i = 0; i < 2; ++i)
#pragma unroll
                for (int j = 0; j < 4; ++j)
                    acc[i][j] = __builtin_amdgcn_mfma_f32_16x16x32_bf16(a[i], b[j], acc[i][j], 0, 0, 0);
        }
        __syncthreads();
    }

#pragma unroll
    for (int i = 0; i < 2; ++i) {
        const int row = bm + w * 32 + 16 * i + quad * 4;
#pragma unroll
        for (int j = 0; j < 4; ++j) {
            const int col = bn + 16 * j + m16;
            const float bv = bias[col];
#pragma unroll
            for (int r = 0; r < 4; ++r) {
                float v = acc[i][j][r] + bv + res[(size_t)(row + r) * N + col];
                out[(size_t)(row + r) * N + col] = v;
            }
        }
    }
}

// ---------------------------------------------------------------------------
// V transpose: Vh fp16 [B*T][C] -> VTt fp16 [(b*H+h)*D + d][T]. 64x64 tiles.
// ---------------------------------------------------------------------------
__global__ __launch_bounds__(256) void vtr_kernel(const u16* __restrict__ Vh,
                                                  u16* __restrict__ VTt) {
    const int t0 = blockIdx.x * 64;
    const int h = blockIdx.y;
    const int b = blockIdx.z;
    const int tid = threadIdx.x;
    __shared__ u16 tl[64][65];
#pragma unroll
    for (int it = 0; it < 4; ++it) {
        int e = tid + it * 256;
        int r = e >> 4, c4 = (e & 15) * 4;
        ushort4 v = *reinterpret_cast<const ushort4*>(
            &Vh[(size_t)(b * TT + t0 + r) * CC + h * DD + c4]);
        tl[c4 + 0][r] = v.x; tl[c4 + 1][r] = v.y; tl[c4 + 2][r] = v.z; tl[c4 + 3][r] = v.w;
    }
    __syncthreads();
#pragma unroll
    for (int it = 0; it < 4; ++it) {
        int e = tid + it * 256;
        int d = e >> 4, s4 = (e & 15) * 4;
        ushort4 o = make_ushort4(tl[d][s4], tl[d][s4 + 1], tl[d][s4 + 2], tl[d][s4 + 3]);
        *reinterpret_cast<ushort4*>(&VTt[(size_t)((b * HH + h) * DD + d) * TT + t0 + s4]) = o;
    }
}

// ---------------------------------------------------------------------------
// MFMA two-pass causal attention (fp16, dbuf, no-max softmax, native exp2).
// Unchanged from R7.
// ---------------------------------------------------------------------------
__global__ __launch_bounds__(256) void attn_kernel(const float* __restrict__ Qf,
                                                   const u16* __restrict__ Kh,
                                                   const u16* __restrict__ VTt,
                                                   float* __restrict__ attn_mean,
                                                   u16* __restrict__ attn_out) {
    const int lid = blockIdx.x;
    const int u = lid & 255;
    const int h = u & 15;
    const int ta = u >> 4;
    const int tt = (lid < 256) ? ta : 31 - ta;
    const int t0 = tt * 64;

    const int tid = threadIdx.x;
    const int lane = tid & 63;
    const int w = tid >> 6;                 // wave 0..3
    const int m16 = lane & 15;
    const int quad = lane >> 4;

    __shared__ u16 smem[2][4][4096];        // 64 KB: [buf][K0,K1,V0,V1]
    __shared__ u16 Pm[2][4096];             // 16 KB: P slots (b0, b1)

    const int arow = w * 16 + m16;          // wave-private fragment row
    const int sw = (m16 & 7) << 3;          // read-side swizzle (u16 units)
    const int rbase = w * 16 + quad * 4;    // C/D row base within tile

    auto KSL = [&](int buf, int b) -> const u16 (*)[64] { return (const u16(*)[64]) & smem[buf][b][0]; };
    auto VSL = [&](int buf, int b) -> const u16 (*)[64] { return (const u16(*)[64]) & smem[buf][2 + b][0]; };

    auto stage_K = [&](int buf, int b, int st) {
#pragma unroll
        for (int it = 0; it < 2; ++it) {
            int c = w * 2 + it;
            int s = c * 8 + (lane >> 3);
            int scol = ((lane & 7) * 8) ^ ((s & 7) << 3);
            glds16(&Kh[(size_t)(b * TT + st * 64 + s) * CC + h * DD + scol],
                   &smem[buf][b][c * 512]);
        }
    };
    auto stage_V = [&](int buf, int b, int st) {
#pragma unroll
        for (int it = 0; it < 2; ++it) {
            int c = w * 2 + it;
            int d = c * 8 + (lane >> 3);
            int scol = ((lane & 7) * 8) ^ ((d & 7) << 3);
            glds16(&VTt[(size_t)((b * HH + h) * DD + d) * TT + st * 64 + scol],
                   &smem[buf][2 + b][c * 512]);
        }
    };
    auto stage_K2 = [&](int buf, int st) { stage_K(buf, 0, st); stage_K(buf, 1, st); };
    auto stage_KV4 = [&](int buf, int st) {
        stage_K2(buf, st); stage_V(buf, 0, st); stage_V(buf, 1, st);
    };

    // ---- Q fragments in registers, scaled by log2e/sqrt(D) ----
    const float QSCALE = 0.125f * 1.4426950408889634f;
    f16x8 qh[2][2];
#pragma unroll
    for (int b = 0; b < 2; ++b) {
        const float* qp = Qf + (size_t)(b * TT + t0 + arow) * CC + h * DD;
#pragma unroll
        for (int ks = 0; ks < 2; ++ks) {
            float4 v0 = *reinterpret_cast<const float4*>(qp + ks * 32 + quad * 8);
            float4 v1 = *reinterpret_cast<const float4*>(qp + ks * 32 + quad * 8 + 4);
            float f[8] = {v0.x, v0.y, v0.z, v0.w, v1.x, v1.y, v1.z, v1.w};
            union { f16x8 v; u16 s[8]; } H;
#pragma unroll
            for (int i = 0; i < 8; ++i) H.s[i] = f2h(f[i] * QSCALE);
            qh[b][ks] = H.v;
        }
    }

    auto compute_S = [&](const f16x8 (&QH)[2], const u16 (*KT)[64],
                         f32x4 (&acc)[4], bool diag) {
        __builtin_amdgcn_s_setprio(1);
#pragma unroll
        for (int ks = 0; ks < 2; ++ks) {
            const int co = (ks * 32 + quad * 8) ^ sw;
#pragma unroll
            for (int j = 0; j < 4; ++j) {
                f16x8 bh = *(const f16x8*)&KT[j * 16 + m16][co];
                acc[j] = __builtin_amdgcn_mfma_f32_16x16x32_f16(QH[ks], bh, acc[j], 0, 0, 0);
            }
        }
        __builtin_amdgcn_s_setprio(0);
        if (diag) {
#pragma unroll
            for (int j = 0; j < 4; ++j)
#pragma unroll
                for (int r = 0; r < 4; ++r)
                    if (j * 16 + m16 > rbase + r) acc[j][r] = -INFINITY;
        }
    };

    auto pv_acc = [&](f32x4 (&O)[4], const u16* Pp, const u16 (*VT)[64]) {
        __builtin_amdgcn_s_setprio(1);
#pragma unroll
        for (int ks = 0; ks < 2; ++ks) {
            const int co = (ks * 32 + quad * 8) ^ sw;
            f16x8 a = *(const f16x8*)&Pp[arow * 64 + co];
#pragma unroll
            for (int j = 0; j < 4; ++j) {
                f16x8 bv = *(const f16x8*)&VT[j * 16 + m16][co];
                O[j] = __builtin_amdgcn_mfma_f32_16x16x32_f16(a, bv, O[j], 0, 0, 0);
            }
        }
        __builtin_amdgcn_s_setprio(0);
    };

    // ---- Pass A ----
    float l_r[2][4] = {};
    stage_K2(0, 0);
    for (int st = 0; st <= tt; ++st) {
        const int cur = st & 1;
        __syncthreads();
        if (st + 1 <= tt) stage_K2(cur ^ 1, st + 1);
        const bool diag = (st == tt);
#pragma unroll
        for (int b = 0; b < 2; ++b) {
            f32x4 acc[4] = {};
            compute_S(qh[b], KSL(cur, b), acc, diag);
#pragma unroll
            for (int r = 0; r < 4; ++r)
                l_r[b][r] += (fexp2(acc[0][r]) + fexp2(acc[1][r])) +
                             (fexp2(acc[2][r]) + fexp2(acc[3][r]));
        }
    }
    __syncthreads();
#pragma unroll
    for (int b = 0; b < 2; ++b)
#pragma unroll
        for (int r = 0; r < 4; ++r) {
            float s = l_r[b][r];
            s += __shfl_xor(s, 1);
            s += __shfl_xor(s, 2);
            s += __shfl_xor(s, 4);
            s += __shfl_xor(s, 8);
            l_r[b][r] = 1.0f / s;
        }

    // ---- Pass B ----
    f32x4 O0[4] = {}, O1[4] = {};
    stage_KV4(0, 0);
    for (int st = 0; st <= tt; ++st) {
        const int cur = st & 1;
        const int s0 = st * 64;
        const bool diag = (st == tt);
        __syncthreads();
        if (st + 1 <= tt) stage_KV4(cur ^ 1, st + 1);

        f32x4 a0[4] = {}, a1[4] = {};
        compute_S(qh[0], KSL(cur, 0), a0, diag);
        compute_S(qh[1], KSL(cur, 1), a1, diag);

#pragma unroll
        for (int j = 0; j < 4; ++j)
#pragma unroll
            for (int r = 0; r < 4; ++r) {
                a0[j][r] = fexp2(a0[j][r]) * l_r[0][r];
                a1[j][r] = fexp2(a1[j][r]) * l_r[1][r];
            }

#pragma unroll
        for (int r = 0; r < 4; ++r) {
            float* mrow = attn_mean + ((size_t)h * TT + t0 + rbase + r) * TT + s0;
#pragma unroll
            for (int j = 0; j < 4; ++j)
                mrow[j * 16 + m16] = 0.5f * (a0[j][r] + a1[j][r]);
        }

#pragma unroll
        for (int r = 0; r < 4; ++r) {
            const int prow = rbase + r;
            const int psw = (prow & 7) << 3;
#pragma unroll
            for (int j = 0; j < 4; ++j) {
                Pm[0][prow * 64 + ((j * 16 + m16) ^ psw)] = f2h(a0[j][r]);
                Pm[1][prow * 64 + ((j * 16 + m16) ^ psw)] = f2h(a1[j][r]);
            }
        }
        pv_acc(O0, &Pm[0][0], VSL(cur, 0));
        pv_acc(O1, &Pm[1][0], VSL(cur, 1));
    }

    // ---- epilogue: att_o bf16 ----
#pragma unroll
    for (int r = 0; r < 4; ++r) {
        const int trow = t0 + rbase + r;
#pragma unroll
        for (int j = 0; j < 4; ++j) {
            attn_out[((size_t)0 * TT + trow) * CC + h * DD + j * 16 + m16] = f2bf(O0[j][r]);
            attn_out[((size_t)1 * TT + trow) * CC + h * DD + j * 16 + m16] = f2bf(O1[j][r]);
        }
    }

    // zero upper triangle of attn_mean rows owned by this block
    const int c0 = (tt + 1) * 64;
    const float4 z4 = make_float4(0.f, 0.f, 0.f, 0.f);
    for (int r = 0; r < 64; ++r) {
        float* row = attn_mean + ((size_t)h * TT + t0 + r) * TT;
        for (int c = c0 + tid * 4; c < TT; c += 1024)
            *reinterpret_cast<float4*>(row + c) = z4;
    }
}

// ---------------------------------------------------------------------------
extern "C" void kernel_launch(void* const* d_in, const int* in_sizes, int n_in,
                              void* d_out, int out_size, void* d_ws, size_t ws_size,
                              hipStream_t stream) {
    const float* x      = (const float*)d_in[0];
    const float* ln1_w  = (const float*)d_in[1];
    const float* ln1_b  = (const float*)d_in[2];
    const float* w_qkv  = (const float*)d_in[3];
    const float* b_qkv  = (const float*)d_in[4];
    const float* w_proj = (const float*)d_in[5];
    const float* b_proj = (const float*)d_in[6];
    const float* ln2_w  = (const float*)d_in[7];
    const float* ln2_b  = (const float*)d_in[8];
    const float* w_fc   = (const float*)d_in[9];
    const float* b_fc   = (const float*)d_in[10];
    const float* w_fc2  = (const float*)d_in[11];
    const float* b_fc2  = (const float*)d_in[12];

    float* out_x    = (float*)d_out;
    float* out_attn = out_x + (size_t)BB * TT * CC;

    char* wp = (char*)d_ws;
    u16* wT_qkv = (u16*)wp;  wp += (size_t)3072 * 1024 * 2;
    u16* wT_proj = (u16*)wp; wp += (size_t)1024 * 1024 * 2;
    u16* wT_fc  = (u16*)wp;  wp += (size_t)4096 * 1024 * 2;
    u16* wT_fc2 = (u16*)wp;  wp += (size_t)1024 * 4096 * 2;
    u16* h_ln   = (u16*)wp;  wp += (size_t)4096 * 1024 * 2;
    u16* att_o  = (u16*)wp;  wp += (size_t)4096 * 1024 * 2;
    u16* h2     = (u16*)wp;  wp += (size_t)4096 * 4096 * 2;
    float* Qf   = (float*)wp; wp += (size_t)4096 * 1024 * 4;
    float* x1   = (float*)wp; wp += (size_t)4096 * 1024 * 4;

    // attn staging buffers overlay h2 (dead until step 6): 3 x 8 MB = 24 MB
    u16* Kh  = h2;
    u16* Vh  = Kh + (size_t)4096 * 1024;
    u16* VTt = Vh + (size_t)4096 * 1024;

    const int M = BB * TT;   // 4096

    // weight convert+transpose (bf16, [N,K])
    wcvt_kernel<<<dim3(3072 / 64, 1024 / 64), 256, 0, stream>>>(w_qkv, wT_qkv, 1024, 3072);
    wcvt_kernel<<<dim3(1024 / 64, 1024 / 64), 256, 0, stream>>>(w_proj, wT_proj, 1024, 1024);
    wcvt_kernel<<<dim3(4096 / 64, 1024 / 64), 256, 0, stream>>>(w_fc, wT_fc, 1024, 4096);
    wcvt_kernel<<<dim3(1024 / 64, 4096 / 64), 256, 0, stream>>>(w_fc2, wT_fc2, 4096, 1024);

    // 1. LN1 -> bf16
    ln_kernel<<<M / 4, 256, 0, stream>>>(x, ln1_w, ln1_b, h_ln);
    // 2. qkv GEMM (256x256 dbuf, grid 192): Q->fp32 Qf, K->Kh fp16, V->Vh fp16
    gemm_db<3><<<dim3(3072 / 256, M / 256), 512, 0, stream>>>(
        h_ln, wT_qkv, b_qkv, Qf, Kh, Vh, M, 3072, 1024);
    // 2b. V transpose
    vtr_kernel<<<dim3(TT / 64, HH, BB), 256, 0, stream>>>(Vh, VTt);
    // 3. attention
    attn_kernel<<<512, 256, 0, stream>>>(Qf, Kh, VTt, out_attn, att_o);
    // 4. x1 = x + att_o @ w_proj + b_proj  (128x64, 4-wave, grid 512)
    gemm_sm<<<dim3(1024 / 64, M / 128), 256, 0, stream>>>(
        att_o, wT_proj, b_proj, x, x1, M, 1024, 1024);
    // 5. LN2 -> bf16
    ln_kernel<<<M / 4, 256, 0, stream>>>(x1, ln2_w, ln2_b, h_ln);
    // 6. h2 = gelu(h_ln @ w_fc + b_fc)  (256x256 dbuf, grid 256)
    gemm_db<1><<<dim3(4096 / 256, M / 256), 512, 0, stream>>>(
        h_ln, wT_fc, b_fc, h2, nullptr, nullptr, M, 4096, 1024);
    // 7. out_x = x1 + h2 @ w_fc2 + b_fc2  (128x64, 4-wave, grid 512)
    gemm_sm<<<dim3(1024 / 64, M / 128), 256, 0, stream>>>(
        h2, wT_fc2, b_fc2, x1, out_x, M, 1024, 4096);
}